// Round 9
// baseline (2245.387 us; speedup 1.0000x reference)
//
#include <hip/hip_runtime.h>
#include <stdint.h>

// Problem dims
#define S_ 256
#define B_ 32
#define H_ 256
#define G4_ 1024   // 4*H
#define HXW (16*132)

typedef short bf16x8 __attribute__((ext_vector_type(8)));
typedef float f32x4  __attribute__((ext_vector_type(4)));

__device__ __forceinline__ unsigned f2bf(float f){
  unsigned u = __float_as_uint(f);
  return (u + 0x7fffu + ((u >> 16) & 1u)) >> 16;   // RNE to bf16
}
__device__ __forceinline__ float bfl(unsigned u){ return __uint_as_float(u << 16); }
__device__ __forceinline__ float bfh(unsigned u){ return __uint_as_float(u & 0xffff0000u); }
__device__ __forceinline__ float sigf(float x){ return 1.0f / (1.0f + __expf(-x)); }
__device__ __forceinline__ float thf(float x){
  x = fminf(fmaxf(x, -15.0f), 15.0f);
  float e = __expf(2.0f * x);
  return (e - 1.0f) / (e + 1.0f);
}

// valid iff both 16b halves have bit14 set (|h|<=1 => raw bf16 bit14 clear;
// 0xAAAAAAAA poison has even bits clear => bit14 clear => invalid)
__device__ __forceinline__ int hval_ok(unsigned long long v){
  return (((unsigned)v & (unsigned)(v >> 32)) & 0x40004000u) == 0x40004000u;
}

// ---------------- prep: embedding gather -> bf16 x [8192][320]; zero all 4
// exchange buffers (first-call safety; steady-state relies on poison/bf16).
__global__ __launch_bounds__(320) void k_prep(const int* __restrict__ words,
                                              const float* __restrict__ emb,
                                              unsigned short* __restrict__ x,
                                              unsigned* __restrict__ zA0,
                                              unsigned* __restrict__ zB0,
                                              unsigned* __restrict__ zA1,
                                              unsigned* __restrict__ zB1){
  int row = blockIdx.x;            // s*32+b
  int e = threadIdx.x;             // 0..319
  int w = words[row];
  x[row * 320 + e] = (e < 300) ? (unsigned short)f2bf(emb[w * 300 + e]) : 0;
  if (e < 256){
    int i = row * 256 + e;         // covers 8192*256 = 2,097,152 u32 = 8 MB
    zA0[i] = 0; zB0[i] = 0; zA1[i] = 0; zB1[i] = 0;
  }
}

// ---------------- pack weights to bf16 (zero-padded K)
__global__ __launch_bounds__(256) void k_packw(
    const float* __restrict__ w0f, const float* __restrict__ w0b,
    const float* __restrict__ w1f, const float* __restrict__ w1b,
    const float* __restrict__ fw,
    unsigned short* __restrict__ wb0f, unsigned short* __restrict__ wb0b,
    unsigned short* __restrict__ wb1f, unsigned short* __restrict__ wb1b,
    unsigned short* __restrict__ fcwb){
  int r = blockIdx.x, tid = threadIdx.x;
  if (r < 2048){
    int rr = r & 1023;
    const float* src = (r < 1024) ? w0f : w0b;
    unsigned short* dst = (r < 1024) ? wb0f : wb0b;
    for (int e = tid; e < 320; e += 256)
      dst[rr * 320 + e] = (e < 300) ? (unsigned short)f2bf(src[rr * 300 + e]) : 0;
  } else if (r < 4096){
    int rr = r & 1023;
    const float* src = (r < 3072) ? w1f : w1b;
    unsigned short* dst = (r < 3072) ? wb1f : wb1b;
    for (int e = tid; e < 512; e += 256)
      dst[rr * 512 + e] = (unsigned short)f2bf(src[rr * 512 + e]);
  } else {
    int rr = r - 4096;
    for (int e = tid; e < 512; e += 256)
      fcwb[rr * 512 + e] = (unsigned short)f2bf(fw[rr * 512 + e]);
  }
}

// ---------------- bf16 MFMA GEMM (both dirs via blockIdx.z)
__global__ __launch_bounds__(256) void k_gemm_bf2(
    const unsigned short* __restrict__ A, int lda, int nSteps,
    const unsigned short* __restrict__ Bf, const unsigned short* __restrict__ Bb,
    const float* __restrict__ b1f, const float* __restrict__ b2f,
    const float* __restrict__ b1b, const float* __restrict__ b2b,
    float* __restrict__ Cf, float* __restrict__ Cb){
  const int z = blockIdx.z;
  const unsigned short* __restrict__ B = z ? Bb : Bf;
  const float* __restrict__ bias1 = z ? b1b : b1f;
  const float* __restrict__ bias2 = z ? b2b : b2f;
  float* __restrict__ C = z ? Cb : Cf;

  __shared__ __align__(16) unsigned As[64 * 20];
  __shared__ __align__(16) unsigned Bs[128 * 20];
  const int tid = threadIdx.x;
  const int w = tid >> 6, lane = tid & 63;
  const int quad = lane >> 4, coln = lane & 15;
  const int m0 = blockIdx.y * 64, n0 = blockIdx.x * 128;

  f32x4 acc[8];
  #pragma unroll
  for (int i = 0; i < 8; ++i){ acc[i][0]=0.f; acc[i][1]=0.f; acc[i][2]=0.f; acc[i][3]=0.f; }

  for (int kt = 0; kt < nSteps; ++kt){
    int k0 = kt * 32;
    __syncthreads();
    {
      int row = tid >> 2, part = tid & 3;
      *(uint4*)&As[row * 20 + part * 4] =
          *(const uint4*)(A + (size_t)(m0 + row) * lda + k0 + part * 8);
    }
    #pragma unroll
    for (int i = 0; i < 2; ++i){
      int idx = tid + 256 * i;
      int row = idx >> 2, part = idx & 3;
      *(uint4*)&Bs[row * 20 + part * 4] =
          *(const uint4*)(B + (size_t)(n0 + row) * lda + k0 + part * 8);
    }
    __syncthreads();
    union { uint4 q; bf16x8 v; } au;
    au.q = *(const uint4*)&As[(w * 16 + coln) * 20 + quad * 4];
    #pragma unroll
    for (int nt = 0; nt < 8; ++nt){
      union { uint4 q; bf16x8 v; } bu;
      bu.q = *(const uint4*)&Bs[(nt * 16 + coln) * 20 + quad * 4];
      acc[nt] = __builtin_amdgcn_mfma_f32_16x16x32_bf16(au.v, bu.v, acc[nt], 0, 0, 0);
    }
  }
  #pragma unroll
  for (int nt = 0; nt < 8; ++nt){
    int col = n0 + nt * 16 + coln;
    float bs = bias1[col] + bias2[col];
    #pragma unroll
    for (int reg = 0; reg < 4; ++reg)
      C[(size_t)(m0 + w * 16 + quad * 4 + reg) * 1024 + col] = acc[nt][reg] + bs;
  }
}

// ---------------- MFMA LSTM recurrence, opportunistic dual-path exchange.
// Producers dual-store each encoded pair: plain write-through store to bufA
// (same-XCD L2 visible) + relaxed/AGENT (sc1) store to bufB (proven path).
// Consumers spin on BOTH (sc0 loads on bufA, sc1 on bufB) and take whichever
// validates first -> deadlock impossible; same-XCD placement only adds speed.
__global__ __launch_bounds__(256, 1) void k_lstm2(
    const float* __restrict__ Gf, const float* __restrict__ Gb,
    const float* __restrict__ Whf, const float* __restrict__ Whb,
    unsigned* __restrict__ hbufA, unsigned* __restrict__ hbufB,
    unsigned short* __restrict__ Hout)         // [S][32][512] bf16
{
  __shared__ __align__(16) unsigned hx[2 * HXW];
  const int wg  = blockIdx.x;
  const int dir = wg >> 3, n = (wg >> 1) & 3, bh = wg & 1;
  const float* __restrict__ G  = dir ? Gb : Gf;
  const float* __restrict__ Wh = dir ? Whb : Whf;
  const int tid  = threadIdx.x;
  const int w    = tid >> 6;
  const int lane = tid & 63;
  const int quad = lane >> 4, coln = lane & 15;

  bf16x8 Wr[32];
  #pragma unroll
  for (int ks = 0; ks < 8; ++ks){
    #pragma unroll
    for (int gt = 0; gt < 4; ++gt){
      const float* wp = Wh + (size_t)(gt * 256 + (n << 6) + (w << 4) + coln) * 256
                        + ks * 32 + quad * 8;
      float4 a = *(const float4*)wp;
      float4 b = *(const float4*)(wp + 4);
      union { unsigned u[4]; bf16x8 v; } tu;
      tu.u[0] = f2bf(a.x) | (f2bf(a.y) << 16);
      tu.u[1] = f2bf(a.z) | (f2bf(a.w) << 16);
      tu.u[2] = f2bf(b.x) | (f2bf(b.y) << 16);
      tu.u[3] = f2bf(b.z) | (f2bf(b.w) << 16);
      Wr[ks * 4 + gt] = tu.v;
    }
  }

  const int gu  = (n << 6) + (w << 4) + coln;
  const int mrw = quad << 2;

  float c0 = 0.f, c1 = 0.f, c2 = 0.f, c3 = 0.f;

  for (int t = 0; t < 256; ++t){
    int s = dir ? (255 - t) : t;
    f32x4 acc[4];
    #pragma unroll
    for (int gt = 0; gt < 4; ++gt){
      const float* gp = G + (size_t)(s * 32 + bh * 16 + mrw) * 1024 + gt * 256 + gu;
      f32x4 a;
      a[0] = gp[0]; a[1] = gp[1024]; a[2] = gp[2048]; a[3] = gp[3072];
      acc[gt] = a;
    }
    unsigned* hxr = &hx[(t & 1) * HXW];
    if (t > 0){
      size_t off = (((size_t)(t - 1) * 2 + dir) * 2 + bh) * 2048;
      const unsigned* hbA = hbufA + off;
      const unsigned* hbB = hbufB + off;
      int row = tid >> 4, kk = tid & 15;
      int n1 = (n + 1) & 3, n2 = (n + 2) & 3, n3 = (n + 3) & 3;
      int b1 = row * 128 + n1 * 32 + kk * 2;
      int b2 = row * 128 + n2 * 32 + kk * 2;
      int b3 = row * 128 + n3 * 32 + kk * 2;
      const unsigned* pA1 = hbA + b1;
      const unsigned* pA2 = hbA + b2;
      const unsigned* pA3 = hbA + b3;
      unsigned long long r1 = 0, r2 = 0, r3 = 0;
      bool d1 = false, d2 = false, d3 = false;
      do {
        unsigned long long a1, a2, a3;
        asm volatile("global_load_dwordx2 %0, %3, off sc0\n\t"
                     "global_load_dwordx2 %1, %4, off sc0\n\t"
                     "global_load_dwordx2 %2, %5, off sc0\n\t"
                     "s_waitcnt vmcnt(0)"
                     : "=&v"(a1), "=&v"(a2), "=&v"(a3)
                     : "v"(pA1), "v"(pA2), "v"(pA3) : "memory");
        if (!d1 && hval_ok(a1)){ r1 = a1; d1 = true; }
        if (!d2 && hval_ok(a2)){ r2 = a2; d2 = true; }
        if (!d3 && hval_ok(a3)){ r3 = a3; d3 = true; }
        if (d1 && d2 && d3) break;
        if (!d1){
          unsigned long long v = __hip_atomic_load(
              (const unsigned long long*)(hbB + b1),
              __ATOMIC_RELAXED, __HIP_MEMORY_SCOPE_AGENT);
          if (hval_ok(v)){ r1 = v; d1 = true; }
        }
        if (!d2){
          unsigned long long v = __hip_atomic_load(
              (const unsigned long long*)(hbB + b2),
              __ATOMIC_RELAXED, __HIP_MEMORY_SCOPE_AGENT);
          if (hval_ok(v)){ r2 = v; d2 = true; }
        }
        if (!d3){
          unsigned long long v = __hip_atomic_load(
              (const unsigned long long*)(hbB + b3),
              __ATOMIC_RELAXED, __HIP_MEMORY_SCOPE_AGENT);
          if (hval_ok(v)){ r3 = v; d3 = true; }
        }
      } while (!(d1 && d2 && d3));
      hxr[row * 132 + n1 * 32 + kk * 2]     = (unsigned)r1 & 0xBFFFBFFFu;
      hxr[row * 132 + n1 * 32 + kk * 2 + 1] = (unsigned)(r1 >> 32) & 0xBFFFBFFFu;
      hxr[row * 132 + n2 * 32 + kk * 2]     = (unsigned)r2 & 0xBFFFBFFFu;
      hxr[row * 132 + n2 * 32 + kk * 2 + 1] = (unsigned)(r2 >> 32) & 0xBFFFBFFFu;
      hxr[row * 132 + n3 * 32 + kk * 2]     = (unsigned)r3 & 0xBFFFBFFFu;
      hxr[row * 132 + n3 * 32 + kk * 2 + 1] = (unsigned)(r3 >> 32) & 0xBFFFBFFFu;
      __syncthreads();
      #pragma unroll
      for (int ks = 0; ks < 8; ++ks){
        union { uint4 q; bf16x8 v; } tu;
        tu.q = *(const uint4*)&hxr[coln * 132 + ks * 16 + quad * 4];
        #pragma unroll
        for (int gt = 0; gt < 4; ++gt)
          acc[gt] = __builtin_amdgcn_mfma_f32_16x16x32_bf16(tu.v, Wr[ks * 4 + gt],
                                                            acc[gt], 0, 0, 0);
      }
    }
    unsigned* hxw = &hx[((t + 1) & 1) * HXW];
    size_t woff = (((size_t)t * 2 + dir) * 2 + bh) * 2048;
    unsigned* hwA = hbufA + woff;
    unsigned* hwB = hbufB + woff;
    float cc[4] = {c0, c1, c2, c3};
    #pragma unroll
    for (int reg = 0; reg < 4; ++reg){
      float gi = sigf(acc[0][reg]);
      float gf = sigf(acc[1][reg]);
      float gg = thf (acc[2][reg]);
      float go = sigf(acc[3][reg]);
      float cv = gf * cc[reg] + gi * gg;
      cc[reg] = cv;
      float hv = go * thf(cv);
      unsigned hb16 = f2bf(hv);
      unsigned other = (unsigned)__shfl_xor((int)hb16, 1);
      if (!(coln & 1)){
        unsigned pair = hb16 | (other << 16);
        hxw[(mrw + reg) * 132 + (gu >> 1)] = pair;
        if (t < 255){
          unsigned enc = pair | 0x40004000u;
          int idx = (mrw + reg) * 128 + (gu >> 1);
          ((volatile unsigned*)hwA)[idx] = enc;      // write-through to own L2
          __hip_atomic_store(hwB + idx, enc,
                             __ATOMIC_RELAXED, __HIP_MEMORY_SCOPE_AGENT);
        }
      }
      Hout[(size_t)(s * 32 + bh * 16 + mrw + reg) * 512 + dir * 256 + gu] =
          (unsigned short)hb16;
    }
    c0 = cc[0]; c1 = cc[1]; c2 = cc[2]; c3 = cc[3];
  }
}

// ---------------- FC: em[row][t] = h1[row][:512].fcw[t][:512] + fcb[t]  (bf16 in)
__global__ __launch_bounds__(64) void k_fc(const unsigned short* __restrict__ h1,
                                           const unsigned short* __restrict__ fw,
                                           const float* __restrict__ fb,
                                           float* __restrict__ em){
  int row = blockIdx.x;
  int lane = threadIdx.x;
  int tag = lane & 31, half = lane >> 5;
  const uint4* hp = (const uint4*)(h1 + (size_t)row * 512 + half * 256);
  const uint4* wp = (const uint4*)(fw + (size_t)tag * 512 + half * 256);
  float acc = 0.0f;
  #pragma unroll 8
  for (int i = 0; i < 32; ++i){
    uint4 h = hp[i], v = wp[i];
    acc += bfl(h.x) * bfl(v.x) + bfh(h.x) * bfh(v.x)
         + bfl(h.y) * bfl(v.y) + bfh(h.y) * bfh(v.y)
         + bfl(h.z) * bfl(v.z) + bfh(h.z) * bfh(v.z)
         + bfl(h.w) * bfl(v.w) + bfh(h.w) * bfh(v.w);
  }
  acc += __shfl_down(acc, 32);
  if (half == 0) em[row * 32 + tag] = acc + fb[tag];
}

// ---------------- CRF: blocks 0..31 viterbi, 32..63 loss. Single wave,
// barrier-free (wave-synchronous LDS), trans column in registers.
__global__ __launch_bounds__(64) void k_crf(const float* __restrict__ em,
                                            const int* __restrict__ tags,
                                            const float* __restrict__ start,
                                            const float* __restrict__ trans,
                                            const float* __restrict__ endv,
                                            int* __restrict__ path,
                                            float* __restrict__ lossb){
  __shared__ float al[32];
  __shared__ unsigned char bp[255][32];
  int b = blockIdx.x & 31, mode = blockIdx.x >> 5;
  int t = threadIdx.x;            // 0..63
  int tg = t & 31;
  float tr_reg[32];
  #pragma unroll
  for (int p = 0; p < 32; ++p) tr_reg[p] = trans[p * 32 + tg];
  float a = start[tg] + em[b * 32 + tg];
  if (mode == 0){
    for (int s = 1; s < 256; ++s){
      if (t < 32) al[t] = a;
      __builtin_amdgcn_s_waitcnt(0);
      float best = -1e30f; int bi = 0;
      for (int p = 0; p < 32; ++p){
        float v = al[p] + tr_reg[p];
        if (v > best){ best = v; bi = p; }   // strict > keeps FIRST max
      }
      if (t < 32){
        a = best + em[(s * 32 + b) * 32 + t];
        bp[s - 1][t] = (unsigned char)bi;
      }
    }
    if (t < 32) al[t] = a;
    __builtin_amdgcn_s_waitcnt(0);
    if (t == 0){
      float best = -1e30f; int bi = 0;
      for (int p = 0; p < 32; ++p){
        float v = al[p] + endv[p];
        if (v > best){ best = v; bi = p; }
      }
      int cur = bi;
      path[255 * 32 + b] = cur;
      for (int s = 254; s >= 0; --s){
        cur = bp[s][cur];
        path[s * 32 + b] = cur;
      }
    }
  } else {
    for (int s = 1; s < 256; ++s){
      if (t < 32) al[t] = a;
      __builtin_amdgcn_s_waitcnt(0);
      float m = -1e30f;
      for (int p = 0; p < 32; ++p){
        float v = al[p] + tr_reg[p];
        m = fmaxf(m, v);
      }
      float ss = 0.0f;
      for (int p = 0; p < 32; ++p)
        ss += __expf(al[p] + tr_reg[p] - m);
      if (t < 32) a = m + __logf(ss) + em[(s * 32 + b) * 32 + t];
    }
    if (t < 32) al[t] = a;
    __builtin_amdgcn_s_waitcnt(0);
    float nsum = 0.0f;
    for (int s = t; s < 256; s += 64){
      int tgd = tags[s * 32 + b];
      nsum += em[(s * 32 + b) * 32 + tgd];
      if (s == 0) nsum += start[tgd];
      else        nsum += trans[tags[(s - 1) * 32 + b] * 32 + tgd];
      if (s == 255) nsum += endv[tgd];
    }
    #pragma unroll
    for (int off = 32; off >= 1; off >>= 1) nsum += __shfl_down(nsum, off);
    if (t == 0){
      float m = -1e30f;
      for (int p = 0; p < 32; ++p) m = fmaxf(m, al[p] + endv[p]);
      float ss = 0.0f;
      for (int p = 0; p < 32; ++p) ss += __expf(al[p] + endv[p] - m);
      lossb[b] = m + __logf(ss) - nsum;
    }
  }
}

// Sum per-batch losses; write as FLOAT (d_out read back as float32).
__global__ __launch_bounds__(64) void k_final(const float* __restrict__ lossb,
                                              float* __restrict__ outp){
  float v = (threadIdx.x < 32) ? lossb[threadIdx.x] : 0.0f;
  #pragma unroll
  for (int off = 32; off >= 1; off >>= 1) v += __shfl_down(v, off);
  if (threadIdx.x == 0) outp[0] = v;
}

extern "C" void kernel_launch(void* const* d_in, const int* in_sizes, int n_in,
                              void* d_out, int out_size, void* d_ws, size_t ws_size,
                              hipStream_t stream){
  const int*   words  = (const int*)d_in[0];
  const int*   tags   = (const int*)d_in[2];
  const float* emb    = (const float*)d_in[3];
  const float* fcw    = (const float*)d_in[4];
  const float* fcb    = (const float*)d_in[5];
  const float* cstart = (const float*)d_in[6];
  const float* cend   = (const float*)d_in[7];
  const float* ctrans = (const float*)d_in[8];
  const float* w_ih[4] = {(const float*)d_in[9],  (const float*)d_in[13],
                          (const float*)d_in[17], (const float*)d_in[21]};
  const float* w_hh[4] = {(const float*)d_in[10], (const float*)d_in[14],
                          (const float*)d_in[18], (const float*)d_in[22]};
  const float* b_ih[4] = {(const float*)d_in[11], (const float*)d_in[15],
                          (const float*)d_in[19], (const float*)d_in[23]};
  const float* b_hh[4] = {(const float*)d_in[12], (const float*)d_in[16],
                          (const float*)d_in[20], (const float*)d_in[24]};

  char* base = (char*)d_ws;
  unsigned short* x    = (unsigned short*)base;                 // 5,242,880 B
  float* Gf            = (float*)(base + 5242880);              // 33,554,432 B
  float* Gb            = (float*)(base + 38797312);             // 33,554,432 B
  unsigned short* h0   = (unsigned short*)(base + 72351744);    // 8,388,608 B
  unsigned short* h1   = (unsigned short*)(base + 80740352);    // 8,388,608 B
  unsigned short* wb0f = (unsigned short*)(base + 89128960);    // 655,360 B
  unsigned short* wb0b = (unsigned short*)(base + 89784320);    // 655,360 B
  unsigned short* wb1f = (unsigned short*)(base + 90439680);    // 1,048,576 B
  unsigned short* wb1b = (unsigned short*)(base + 91488256);    // 1,048,576 B
  unsigned short* fcwb = (unsigned short*)(base + 92536832);    // 32,768 B
  float* lossb         = (float*)(base + 92569600);             // 128 B
  unsigned* hbufB0     = (unsigned*)(base + 92569728);          // 8,388,608 B
  unsigned* hbufB1     = (unsigned*)(base + 100958336);         // 8,388,608 B
  float* em            = Gf;                    // overlay: Gf dead after L1 lstm
  unsigned* hbufA0 = (unsigned*)h1;  // L0 fast buf (poison/zeroed => invalid)
  unsigned* hbufA1 = (unsigned*)h0;  // L1 fast buf (L0 bf16 |h|<=1 => invalid)

  k_prep<<<8192, 320, 0, stream>>>(words, emb, x, hbufA0, hbufB0, hbufA1, hbufB1);
  k_packw<<<4128, 256, 0, stream>>>(w_ih[0], w_ih[1], w_ih[2], w_ih[3], fcw,
                                    wb0f, wb0b, wb1f, wb1b, fcwb);

  // layer 0 input projections (K padded to 320), both dirs in one launch
  k_gemm_bf2<<<dim3(8, 128, 2), 256, 0, stream>>>(x, 320, 10, wb0f, wb0b,
                                                  b_ih[0], b_hh[0], b_ih[1], b_hh[1],
                                                  Gf, Gb);
  k_lstm2<<<16, 256, 0, stream>>>(Gf, Gb, w_hh[0], w_hh[1], hbufA0, hbufB0, h0);

  // layer 1 input projections (K=512)
  k_gemm_bf2<<<dim3(8, 128, 2), 256, 0, stream>>>(h0, 512, 16, wb1f, wb1b,
                                                  b_ih[2], b_hh[2], b_ih[3], b_hh[3],
                                                  Gf, Gb);
  k_lstm2<<<16, 256, 0, stream>>>(Gf, Gb, w_hh[2], w_hh[3], hbufA1, hbufB1, h1);

  k_fc<<<8192, 64, 0, stream>>>(h1, fcwb, fcb, em);

  k_crf<<<64, 64, 0, stream>>>(em, tags, cstart, ctrans, cend, (int*)d_out, lossb);
  k_final<<<1, 64, 0, stream>>>(lossb, ((float*)d_out) + (out_size - 1));
}